// Round 2
// baseline (1488.193 us; speedup 1.0000x reference)
//
#include <hip/hip_runtime.h>

// LSTM decoder: B=256, H=512, L=2, T=64, O=7
// Persistent kernel, round 9:
//  - KEY: steady-state phases reuse the previous phase's x-chunks (already
//    staged in LDS) as this phase's h-chunks — identical data, identical
//    layout (layer0[t+1].h = H0[t] = layer1[t].x, layer1[t].h = H1[t-1] =
//    layer0[t].x). No h global loads, no h LDS writes, phases 2..127.
//  - sentinel signaling (0xFF fill; 0xFFFF = f16 NaN, never produced);
//    per-dword validation with sc0sc1 bypass retry. No flags, no polls.
//  - raw s_barrier (lgkmcnt only) — x-loads/stores stay in flight across
//    barriers with counted vmcnt.
//  - h-store: single 16B dwordx4 sc0sc1 (round-7 coalescing); WAR hazard
//    handled by keepA reg quad released only after a vmcnt that retires
//    the store (first wait of the NEXT phase).
//  - epilogue scratch at LDS 64KB+ (par buffers must survive into next
//    phase as h) -> 69KB dynamic LDS (gfx950 allows up to 160KB/WG).
//  - FC fused in tail, 16B vectorized loads + sentinel validation.

#define TT 64
#define NO 7

typedef _Float16 h16;
typedef __attribute__((ext_vector_type(8))) _Float16 half8;
typedef __attribute__((ext_vector_type(4))) float f32x4;
typedef __attribute__((ext_vector_type(4))) int i32x4;

__device__ __forceinline__ float sigf(float x)   { return 1.f / (1.f + __expf(-x)); }
__device__ __forceinline__ float tanhf_(float x) { return 1.f - 2.f / (__expf(2.f * x) + 1.f); }

// ---------------- prologue: pack [W_ih | W_hh] -> f16 Wc[l][n][k], k-major ----
__global__ __launch_bounds__(256) void prep_weights(
    const float* __restrict__ Wih, const float* __restrict__ Whh,
    h16* __restrict__ Wc)
{
    size_t gid = (size_t)blockIdx.x * 256 + threadIdx.x;
    size_t base = gid * 8;
    int l = (int)(base >> 21);
    int rem = (int)(base & ((1u << 21) - 1));
    int n = rem >> 10;
    int k = rem & 1023;
    const float* src = (k < 512)
        ? (Wih + ((size_t)l * 2048 + n) * 512 + k)
        : (Whh + ((size_t)l * 2048 + n) * 512 + (k - 512));
    const float4* s4 = (const float4*)src;
    float4 a = s4[0];
    float4 b = s4[1];
    half8 o;
    o[0] = (h16)a.x; o[1] = (h16)a.y; o[2] = (h16)a.z; o[3] = (h16)a.w;
    o[4] = (h16)b.x; o[5] = (h16)b.y; o[6] = (h16)b.z; o[7] = (h16)b.w;
    *(half8*)(Wc + base) = o;
}

// ---------------- prologue: init Xinit/H0init/H1init + bias ------------------
__global__ __launch_bounds__(256) void init_misc(
    const float* __restrict__ x, const float* __restrict__ h0,
    const float* __restrict__ bih, const float* __restrict__ bhh,
    h16* __restrict__ Xinit, h16* __restrict__ H0init, h16* __restrict__ H1init,
    float* __restrict__ bias)
{
    int i = blockIdx.x * 256 + threadIdx.x;
    if (i < 131072) { Xinit[i]  = (h16)x[i];           return; }
    i -= 131072;
    if (i < 131072) { H0init[i] = (h16)h0[i];          return; }
    i -= 131072;
    if (i < 131072) { H1init[i] = (h16)h0[131072 + i]; return; }
    i -= 131072;
    if (i < 4096) bias[i] = bih[i] + bhh[i];
}

// ---------------- persistent LSTM ------------------------------------------
// 256 WGs x 256 thr, 1 WG/CU. XCD-pinned: m = (wg&7)>>1, us = (wg>>3)+(wg&1)*32.
// WG: 64-row m-tile x 8 h-units. Wave w: rows (w>>1)*32..+32, units (w&1)*4..+4.
__global__ __launch_bounds__(256, 1) void lstm_persist(
    const h16* __restrict__ Wc, const float* __restrict__ bias,
    const float* __restrict__ c0in,
    const h16* __restrict__ Xinit, const h16* __restrict__ H0init,
    const h16* __restrict__ H1init,
    h16* __restrict__ H0, h16* __restrict__ H1,
    float* __restrict__ h_st, float* __restrict__ c_st,
    const float* __restrict__ Wfc, const float* __restrict__ bfc,
    float* __restrict__ out)
{
    extern __shared__ char ldsraw[];   // 70656B: 2x32KB par + 4KB scrw + 1KB hbuf

    const int wg   = blockIdx.x;
    const int m    = (wg & 7) >> 1;               // XCD-pinned m-group
    const int us   = (wg >> 3) + (wg & 1) * 32;   // unit slice 0..63
    const int tid  = threadIdx.x, w = tid >> 6, lane = tid & 63;
    const int u0   = us * 8;
    const int m0   = m * 64;
    const int rowbase = m0 + (w >> 1) * 32;
    const int ubase   = u0 + (w & 1) * 4;
    const int mcol = lane & 15, kq = lane >> 4;
    const int nrow = (mcol & 3) * 512 + ubase + (mcol >> 2);
    const int lrow = (w >> 1) * 32 + mcol;     // local row of m-subtile 0
    const int sw   = mcol & 7;                 // LDS XOR swizzle key
    const int lrloc = (w >> 1) * 32 + (lane >> 2);   // epilogue local row
    const int luloc = (w & 1) * 4 + (lane & 3);      // epilogue local unit

    // ---- B fragments for both layers -> registers/AGPRs (loaded once) ----
    half8 Bw0[32], Bw1[32];
#pragma unroll
    for (int ks = 0; ks < 32; ++ks) {
        Bw0[ks] = *(const half8*)(Wc + (size_t)nrow * 1024 + ks * 32 + kq * 8);
        Bw1[ks] = *(const half8*)(Wc + (size_t)(2048 + nrow) * 1024 + ks * 32 + kq * 8);
    }

    // ---- epilogue lane mapping (round-2/5/6 verified) ----
    const int eunit = ubase + (lane & 3);
    const int erow0 = rowbase + (lane >> 2);   // m-subtile 0; +16 for subtile 1
    float4 bz0 = make_float4(bias[eunit], bias[512 + eunit],
                             bias[1024 + eunit], bias[1536 + eunit]);
    float4 bz1 = make_float4(bias[2048 + eunit], bias[2048 + 512 + eunit],
                             bias[2048 + 1024 + eunit], bias[2048 + 1536 + eunit]);

    float creg[2][2], hreg[2][2];
#pragma unroll
    for (int mt = 0; mt < 2; ++mt) {
        creg[0][mt] = c0in[(erow0 + mt * 16) * 512 + eunit];
        creg[1][mt] = c0in[131072 + (erow0 + mt * 16) * 512 + eunit];
        hreg[0][mt] = 0.f; hreg[1][mt] = 0.f;
    }

    i32x4 keepA = {0, 0, 0, 0};   // h-store data; live until store retires

// raw workgroup barrier: LDS ordering only — global loads/stores stay in
// flight across it (the point; __syncthreads would drain vmcnt(0)).
#define BARRIER() do {                                                        \
    asm volatile("s_waitcnt lgkmcnt(0)" ::: "memory");                        \
    __builtin_amdgcn_s_barrier();                                             \
    asm volatile("" ::: "memory");                                            \
} while (0)

// plain CACHED 16B loads of k-half `cs` (0/1) of the 64-row tile at BASE
// (row stride 1024B) into tmp[TB..TB+7]. Issue order defines vmcnt drains.
#define ISSUE_CHUNK(BASE, cs, TB) do {                                        \
    _Pragma("unroll")                                                         \
    for (int j = 0; j < 8; ++j) {                                             \
        int g = j * 256 + tid;                                                \
        int voff = (g >> 5) * 1024 + (cs) * 512 + (g & 31) * 16;              \
        asm volatile("global_load_dwordx4 %0, %1, %2"                         \
            : "=v"(tmp[(TB) + j]) : "v"(voff), "s"(BASE) : "memory");         \
    } } while (0)

// drain 8 loads (oldest-first), VALIDATE vs 0xFF sentinel (per-dword; finite
// f16 pairs are never 0xFFFFFFFF), retry with sc0sc1 bypass, write LDS `par`
// with XOR swizzle. NB = outstanding-1 at entry (per wave).
#define WRITE_CHUNK(par, TB, NB, BASE, cs) do {                               \
    _Pragma("unroll")                                                         \
    for (int j = 0; j < 8; ++j) {                                             \
        asm volatile("s_waitcnt vmcnt(%0)" :: "i"((NB) - j) : "memory");      \
        __builtin_amdgcn_sched_barrier(0);                                    \
        int g = j * 256 + tid;                                                \
        int row = g >> 5, bc = g & 31;                                        \
        int voff = row * 1024 + (cs) * 512 + bc * 16;                         \
        i32x4 v = tmp[(TB) + j];                                              \
        while (__builtin_expect((v[0] == -1) | (v[1] == -1) |                 \
                                (v[2] == -1) | (v[3] == -1), 0)) {            \
            asm volatile("global_load_dwordx4 %0, %1, %2 sc0 sc1\n\t"         \
                         "s_waitcnt vmcnt(0)"                                 \
                : "=v"(v) : "v"(voff), "s"(BASE) : "memory");                 \
        }                                                                     \
        *(i32x4*)(ldsraw + (par) * 32768 + row * 512 +                        \
                  ((bc ^ (row & 7)) * 16)) = v;                               \
    } } while (0)

// 8 k-steps of MFMA from LDS buffer `par` against B fragments BW[CO..CO+7]
#define MFMA_CHUNK(par, CO, BW) do {                                          \
    _Pragma("unroll")                                                         \
    for (int ks = 0; ks < 8; ++ks) {                                          \
        half8 a0 = *(const half8*)(ldsraw + (par) * 32768 + lrow * 512 +      \
                      (((kq + 4 * ks) ^ sw) * 16));                           \
        half8 a1 = *(const half8*)(ldsraw + (par) * 32768 +                   \
                      (lrow + 16) * 512 + (((kq + 4 * ks) ^ sw) * 16));       \
        acc0 = __builtin_amdgcn_mfma_f32_16x16x32_f16(a0, (BW)[(CO) + ks],    \
                                                      acc0, 0, 0, 0);         \
        acc1 = __builtin_amdgcn_mfma_f32_16x16x32_f16(a1, (BW)[(CO) + ks],    \
                                                      acc1, 0, 0, 0);         \
    } } while (0)

// epilogue: transpose via LDS scrw (@64KB), cell math, hbuf gather (@69632),
// single coalesced 16B sc0sc1 flush by wave 0. Store data parked in keepA
// (released next phase after a vmcnt retires the store).
#define EPILOGUE(BZ, CREG, HREG, HDST) do {                                   \
    float* scrw = (float*)(ldsraw + 65536 + w * 1024);                        \
    h16* hbuf = (h16*)(ldsraw + 69632);                                       \
    _Pragma("unroll")                                                         \
    for (int mt = 0; mt < 2; ++mt) {                                          \
        f32x4 accv = mt ? acc1 : acc0;                                        \
        _Pragma("unroll")                                                     \
        for (int rr = 0; rr < 4; ++rr)                                        \
            scrw[(kq * 4 + rr) * 16 + mcol] = accv[rr];                       \
        float4 g4 = *(const float4*)&scrw[(lane >> 2) * 16 + (lane & 3) * 4]; \
        float iv = sigf(g4.x + (BZ).x);                                       \
        float fv = sigf(g4.y + (BZ).y);                                       \
        float gv = tanhf_(g4.z + (BZ).z);                                     \
        float ov = sigf(g4.w + (BZ).w);                                       \
        float cc = fv * (CREG)[mt] + iv * gv;                                 \
        float hh = ov * tanhf_(cc);                                           \
        (CREG)[mt] = cc; (HREG)[mt] = hh;                                     \
        hbuf[(lrloc + mt * 16) * 8 + luloc] = (h16)hh;                        \
    }                                                                         \
    BARRIER();                                                                \
    if (tid < 64) {                                                           \
        keepA = *(const i32x4*)(ldsraw + 69632 + tid * 16);                   \
        int voff = (m0 + tid) * 1024 + u0 * 2;                                \
        asm volatile("global_store_dwordx4 %0, %1, %2 sc0 sc1"                \
            :: "v"(voff), "v"(keepA), "s"((const void*)(HDST)) : "memory");   \
    }                                                                         \
} while (0)

// FULL phase (t=0 only): h loaded from global into par0/1, then overwritten
// by x after the h-MFMAs. Ends with x (=this phase's output source data for
// the next phase's h) resident in par0/1.
#define PHASE_FULL(XSRC, HSRC, BW, BZ, CREG, HREG, HDST) do {                 \
    const char* bx = (const char*)(XSRC) + (size_t)m0 * 1024;                 \
    const char* bh = (const char*)(HSRC) + (size_t)m0 * 1024;                 \
    i32x4 tmp[16];                                                            \
    ISSUE_CHUNK(bh, 0, 0);                                                    \
    ISSUE_CHUNK(bh, 1, 8);                                                    \
    f32x4 acc0 = {0.f,0.f,0.f,0.f}, acc1 = {0.f,0.f,0.f,0.f};                 \
    asm volatile("s_waitcnt vmcnt(16)" ::: "memory");                         \
    __builtin_amdgcn_sched_barrier(0);                                        \
    asm volatile("" : "+v"(keepA));          /* store retired: WAR release */ \
    WRITE_CHUNK(0, 0, 15, bh, 0);                                             \
    WRITE_CHUNK(1, 8, 7, bh, 1);                                              \
    ISSUE_CHUNK(bx, 0, 0);                                                    \
    ISSUE_CHUNK(bx, 1, 8);                                                    \
    BARRIER();                                                                \
    MFMA_CHUNK(0, 16, BW);                                                    \
    MFMA_CHUNK(1, 24, BW);                                                    \
    BARRIER();                                                                \
    WRITE_CHUNK(0, 0, 15, bx, 0);                                             \
    WRITE_CHUNK(1, 8, 7, bx, 1);                                              \
    BARRIER();                                                                \
    MFMA_CHUNK(0, 0, BW);                                                     \
    MFMA_CHUNK(1, 8, BW);                                                     \
    EPILOGUE(BZ, CREG, HREG, HDST);                                           \
} while (0)

// FAST phase (steady state): h already in par0/1 (= previous phase's x).
// Issue x, MFMA h from resident LDS (hides x flight), barrier, validate+
// stage x over par0/1, barrier, MFMA x, epilogue.
#define PHASE_FAST(XSRC, BW, BZ, CREG, HREG, HDST) do {                       \
    const char* bx = (const char*)(XSRC) + (size_t)m0 * 1024;                 \
    i32x4 tmp[16];                                                            \
    ISSUE_CHUNK(bx, 0, 0);                                                    \
    ISSUE_CHUNK(bx, 1, 8);                                                    \
    f32x4 acc0 = {0.f,0.f,0.f,0.f}, acc1 = {0.f,0.f,0.f,0.f};                 \
    MFMA_CHUNK(0, 16, BW);                                                    \
    MFMA_CHUNK(1, 24, BW);                                                    \
    BARRIER();                                                                \
    asm volatile("s_waitcnt vmcnt(15)" ::: "memory");                         \
    __builtin_amdgcn_sched_barrier(0);                                        \
    asm volatile("" : "+v"(keepA));          /* store retired: WAR release */ \
    WRITE_CHUNK(0, 0, 15, bx, 0);                                             \
    WRITE_CHUNK(1, 8, 7, bx, 1);                                              \
    BARRIER();                                                                \
    MFMA_CHUNK(0, 0, BW);                                                     \
    MFMA_CHUNK(1, 8, BW);                                                     \
    EPILOGUE(BZ, CREG, HREG, HDST);                                           \
} while (0)

    // t = 0: both layers load h from global (H0init / H1init).
    PHASE_FULL(Xinit, H0init, Bw0, bz0, creg[0], hreg[0], H0);
    PHASE_FULL(H0,    H1init, Bw1, bz1, creg[1], hreg[1], H1);
    // t >= 1: h = previous phase's x, already in LDS.
#pragma unroll 1
    for (int t = 1; t < TT; ++t) {
        PHASE_FAST(H1 + (size_t)(t - 1) * 131072, Bw0, bz0, creg[0], hreg[0],
                   H0 + (size_t)t * 131072);
        PHASE_FAST(H0 + (size_t)t * 131072, Bw1, bz1, creg[1], hreg[1],
                   H1 + (size_t)t * 131072);
    }

    // retire final h-store before releasing keepA / reusing LDS
    asm volatile("s_waitcnt vmcnt(0)" ::: "memory");
    asm volatile("" : "+v"(keepA));

    // ---- final hT / cT (normal stores; kernel-end release flushes) ----
#pragma unroll
    for (int mt = 0; mt < 2; ++mt) {
        int idx = (erow0 + mt * 16) * 512 + eunit;
        h_st[idx]          = hreg[0][mt];
        h_st[131072 + idx] = hreg[1][mt];
        c_st[idx]          = creg[0][mt];
        c_st[131072 + idx] = creg[1][mt];
    }

    // ---- fused FC over all stored h1(t): (T*B) x 7, K=512 ----
    // WG handles 64 flat rows (row = t*256 + b); 16B vectorized loads with
    // per-dword sentinel validation (straggler stores spin-waited per lane).
    {
        __syncthreads();
        float* wl = (float*)ldsraw;
        for (int i = tid; i < NO * 512; i += 256) wl[i] = Wfc[i];
        __syncthreads();
        const int fcw = tid >> 6, fl = tid & 63;
#pragma unroll 1
        for (int rr = 0; rr < 16; ++rr) {
            const int row = wg * 64 + fcw * 16 + rr;
            const h16* hr = H1 + (size_t)row * 512;
            i32x4 hv = *(const i32x4*)(hr + fl * 8);
            while (__builtin_expect((hv[0] == -1) | (hv[1] == -1) |
                                    (hv[2] == -1) | (hv[3] == -1), 0)) {
                const h16* hp = hr + fl * 8;
                asm volatile("global_load_dwordx4 %0, %1, off sc0 sc1\n\t"
                             "s_waitcnt vmcnt(0)"
                    : "=v"(hv) : "v"(hp) : "memory");
            }
            half8 h8 = __builtin_bit_cast(half8, hv);
            float acc[NO] = {0.f, 0.f, 0.f, 0.f, 0.f, 0.f, 0.f};
#pragma unroll
            for (int j = 0; j < 8; ++j) {
                float hvf = (float)h8[j];
#pragma unroll
                for (int o = 0; o < NO; ++o)
                    acc[o] += hvf * wl[o * 512 + fl * 8 + j];
            }
#pragma unroll
            for (int o = 0; o < NO; ++o)
#pragma unroll
                for (int off = 32; off; off >>= 1)
                    acc[o] += __shfl_down(acc[o], off);
            if (fl == 0) {
                const int t = row >> 8, b = row & 255;
#pragma unroll
                for (int o = 0; o < NO; ++o)
                    out[b * (TT * NO) + t * NO + o] = acc[o] + bfc[o];
            }
        }
    }
}

extern "C" void kernel_launch(void* const* d_in, const int* in_sizes, int n_in,
                              void* d_out, int out_size, void* d_ws, size_t ws_size,
                              hipStream_t stream)
{
    (void)in_sizes; (void)n_in; (void)out_size; (void)ws_size;
    const float* x   = (const float*)d_in[0];
    const float* h0  = (const float*)d_in[1];
    const float* c0  = (const float*)d_in[2];
    const float* Wih = (const float*)d_in[3];
    const float* Whh = (const float*)d_in[4];
    const float* bih = (const float*)d_in[5];
    const float* bhh = (const float*)d_in[6];
    const float* Wfc = (const float*)d_in[7];
    const float* bfc = (const float*)d_in[8];

    float* outf = (float*)d_out;                 // decoded (256*64*7)
    float* h_st = outf + 114688;                 // hT (2,256,512)
    float* c_st = h_st + 262144;                 // cT (2,256,512)

    char* ws = (char*)d_ws;
    h16*      Wc     = (h16*)ws;                         // 8 MB
    float*    bias   = (float*)(ws + 8388608);           // 16 KB
    h16*      Xinit  = (h16*)(ws + 8404992);             // 256 KB
    h16*      H0init = (h16*)(ws + 8667136);             // 256 KB
    h16*      H1init = (h16*)(ws + 8929280);             // 256 KB
    h16*      H0     = (h16*)(ws + 9191424);             // 16 MB (64 steps)
    h16*      H1     = (h16*)(ws + 25968640);            // 16 MB (64 steps)

    static bool lds_set = false;
    if (!lds_set) {
        hipFuncSetAttribute(reinterpret_cast<const void*>(&lstm_persist),
                            hipFuncAttributeMaxDynamicSharedMemorySize, 70656);
        lds_set = true;
    }

    prep_weights<<<2048, 256, 0, stream>>>(Wih, Whh, Wc);
    init_misc<<<1552, 256, 0, stream>>>(x, h0, bih, bhh, Xinit, H0init, H1init, bias);
    // sentinel-fill H0|H1 (contiguous 32 MB): 0xFFFF f16 = NaN, never produced
    hipMemsetAsync(H0, 0xFF, 33554432, stream);
    lstm_persist<<<256, 256, 70656, stream>>>(Wc, bias, c0, Xinit, H0init, H1init,
                                              H0, H1, h_st, c_st, Wfc, bfc, outf);
}

// Round 7
// 821.866 us; speedup vs baseline: 1.8107x; 1.8107x over previous
//
#include <hip/hip_runtime.h>

// LSTM decoder: B=256, H=512, L=2, T=64, O=7
// Round 14 = CONSOLIDATION: round-0 proven kernel (751us lstm / 825us total)
// with lstm_persist + fc_kernel byte-identical; only change is host-side:
// prep_weights + init_misc + flags-memset fused into ONE prologue kernel
// (disjoint blockIdx ranges, elementwise, no sync) to drop 2 dispatch gaps.
//
// The flags x LDS-h-reuse composition failed 3/3 (0.23 / crash / NaN) with
// varying signatures -> compiler-level fragility (active counted-vmcnt waits
// broken by spill-inserted VMEM ops). Abandoned pending disasm access.
// Next experiment (from this banked baseline): h-reuse via REGISTERS (keep
// x A-fragments in VGPRs across the phase boundary; no LDS lifetime or
// barrier changes; risk confined to VGPR_Count, visible in the bench).

#define TT 64
#define NO 7

typedef _Float16 h16;
typedef __attribute__((ext_vector_type(8))) _Float16 half8;
typedef __attribute__((ext_vector_type(4))) float f32x4;
typedef __attribute__((ext_vector_type(4))) int i32x4;

__device__ __forceinline__ float sigf(float x)   { return 1.f / (1.f + __expf(-x)); }
__device__ __forceinline__ float tanhf_(float x) { return 1.f - 2.f / (__expf(2.f * x) + 1.f); }

// ---------------- fused prologue -------------------------------------------
// blocks [0,2048): pack [W_ih | W_hh] -> f16 Wc[l][n][k], k-major (8 h16/thr)
// blocks [2048,3600): Xinit/H0init/H1init + bias
// blocks [3600,3728): zero the 512KB flag array (16B/thr)
__global__ __launch_bounds__(256) void prologue(
    const float* __restrict__ Wih, const float* __restrict__ Whh,
    h16* __restrict__ Wc,
    const float* __restrict__ x, const float* __restrict__ h0,
    const float* __restrict__ bih, const float* __restrict__ bhh,
    h16* __restrict__ Xinit, h16* __restrict__ H0init, h16* __restrict__ H1init,
    float* __restrict__ bias, unsigned* __restrict__ flags)
{
    int blk = blockIdx.x;
    if (blk < 2048) {
        size_t gid = (size_t)blk * 256 + threadIdx.x;
        size_t base = gid * 8;
        int l = (int)(base >> 21);
        int rem = (int)(base & ((1u << 21) - 1));
        int n = rem >> 10;
        int k = rem & 1023;
        const float* src = (k < 512)
            ? (Wih + ((size_t)l * 2048 + n) * 512 + k)
            : (Whh + ((size_t)l * 2048 + n) * 512 + (k - 512));
        const float4* s4 = (const float4*)src;
        float4 a = s4[0];
        float4 b = s4[1];
        half8 o;
        o[0] = (h16)a.x; o[1] = (h16)a.y; o[2] = (h16)a.z; o[3] = (h16)a.w;
        o[4] = (h16)b.x; o[5] = (h16)b.y; o[6] = (h16)b.z; o[7] = (h16)b.w;
        *(half8*)(Wc + base) = o;
        return;
    }
    blk -= 2048;
    if (blk < 1552) {
        int i = blk * 256 + threadIdx.x;
        if (i < 131072) { Xinit[i]  = (h16)x[i];           return; }
        i -= 131072;
        if (i < 131072) { H0init[i] = (h16)h0[i];          return; }
        i -= 131072;
        if (i < 131072) { H1init[i] = (h16)h0[131072 + i]; return; }
        i -= 131072;
        if (i < 4096) bias[i] = bih[i] + bhh[i];
        return;
    }
    blk -= 1552;
    // flags zero: 128 blocks x 256 threads x 16B = 512KB
    i32x4 z = {0, 0, 0, 0};
    *(i32x4*)(flags + (size_t)(blk * 256 + threadIdx.x) * 4) = z;
}

// ---------------- persistent LSTM (round-0 PROVEN kernel, verbatim) ---------
// 256 WGs x 256 thr, 1 WG/CU. XCD-pinned: m = (wg&7)>>1, us = (wg>>3)+(wg&1)*32.
// WG: 64-row m-tile x 8 h-units. Wave w: rows (w>>1)*32..+32, units (w&1)*4..+4
// (16 gate-cols, col = 4*ulocal + gate).
__global__ __launch_bounds__(256, 1) void lstm_persist(
    const h16* __restrict__ Wc, const float* __restrict__ bias,
    const float* __restrict__ c0in,
    const h16* __restrict__ Xinit, const h16* __restrict__ H0init,
    const h16* __restrict__ H1init,
    h16* __restrict__ H0, h16* __restrict__ H1,
    float* __restrict__ h_st, float* __restrict__ c_st,
    unsigned* __restrict__ flags)
{
    __shared__ char ldsraw[65536];   // 2 x 32KB A-chunk double buffer

    const int wg   = blockIdx.x;
    const int m    = (wg & 7) >> 1;               // XCD-pinned m-group
    const int us   = (wg >> 3) + (wg & 1) * 32;   // unit slice 0..63
    const int myoct = us >> 3;
    const int tid  = threadIdx.x, w = tid >> 6, lane = tid & 63;
    const int u0   = us * 8;
    const int m0   = m * 64;
    const int rowbase = m0 + (w >> 1) * 32;
    const int ubase   = u0 + (w & 1) * 4;
    const int mcol = lane & 15, kq = lane >> 4;
    const int nrow = (mcol & 3) * 512 + ubase + (mcol >> 2);
    const int lrow = (w >> 1) * 32 + mcol;     // local row of m-subtile 0
    const int sw   = mcol & 7;                 // LDS XOR swizzle key
    const int lrloc = (w >> 1) * 32 + (lane >> 2);   // epilogue local row
    const int luloc = (w & 1) * 4 + (lane & 3);      // epilogue local unit

    // ---- B fragments for both layers -> registers/AGPRs (loaded once) ----
    half8 Bw0[32], Bw1[32];
#pragma unroll
    for (int ks = 0; ks < 32; ++ks) {
        Bw0[ks] = *(const half8*)(Wc + (size_t)nrow * 1024 + ks * 32 + kq * 8);
        Bw1[ks] = *(const half8*)(Wc + (size_t)(2048 + nrow) * 1024 + ks * 32 + kq * 8);
    }

    // ---- epilogue lane mapping (round-2/5/6 verified) ----
    const int eunit = ubase + (lane & 3);
    const int erow0 = rowbase + (lane >> 2);   // m-subtile 0; +16 for subtile 1
    float4 bz0 = make_float4(bias[eunit], bias[512 + eunit],
                             bias[1024 + eunit], bias[1536 + eunit]);
    float4 bz1 = make_float4(bias[2048 + eunit], bias[2048 + 512 + eunit],
                             bias[2048 + 1024 + eunit], bias[2048 + 1536 + eunit]);

    float creg[2][2], hreg[2][2];
#pragma unroll
    for (int mt = 0; mt < 2; ++mt) {
        creg[0][mt] = c0in[(erow0 + mt * 16) * 512 + eunit];
        creg[1][mt] = c0in[131072 + (erow0 + mt * 16) * 512 + eunit];
        hreg[0][mt] = 0.f; hreg[1][mt] = 0.f;
    }

// plain CACHED 16B loads of k-half `cs` (0/1) of the 64-row tile at BASE
// (row stride 1024B) into tmp[TB..TB+7]. Issue order defines vmcnt drains.
#define ISSUE_CHUNK(BASE, cs, TB) do {                                        \
    _Pragma("unroll")                                                         \
    for (int j = 0; j < 8; ++j) {                                             \
        int g = j * 256 + tid;                                                \
        int voff = (g >> 5) * 1024 + (cs) * 512 + (g & 31) * 16;              \
        asm volatile("global_load_dwordx4 %0, %1, %2"                         \
            : "=v"(tmp[(TB) + j]) : "v"(voff), "s"(BASE) : "memory");         \
    } } while (0)

// drain 8 loads (oldest-first) into LDS buffer `par` with XOR swizzle.
// NB = (outstanding when entering) - 1.
#define WRITE_CHUNK(par, TB, NB) do {                                         \
    _Pragma("unroll")                                                         \
    for (int j = 0; j < 8; ++j) {                                             \
        asm volatile("s_waitcnt vmcnt(%0)" :: "i"((NB) - j) : "memory");      \
        int g = j * 256 + tid;                                                \
        int row = g >> 5, bc = g & 31;                                        \
        *(i32x4*)(ldsraw + (par) * 32768 + row * 512 +                        \
                  ((bc ^ (row & 7)) * 16)) = tmp[(TB) + j];                   \
    } } while (0)

// 8 k-steps of MFMA from LDS buffer `par` against B fragments BW[CO..CO+7]
#define MFMA_CHUNK(par, CO, BW) do {                                          \
    _Pragma("unroll")                                                         \
    for (int ks = 0; ks < 8; ++ks) {                                          \
        half8 a0 = *(const half8*)(ldsraw + (par) * 32768 + lrow * 512 +      \
                      (((kq + 4 * ks) ^ sw) * 16));                           \
        half8 a1 = *(const half8*)(ldsraw + (par) * 32768 +                   \
                      (lrow + 16) * 512 + (((kq + 4 * ks) ^ sw) * 16));       \
        acc0 = __builtin_amdgcn_mfma_f32_16x16x32_f16(a0, (BW)[(CO) + ks],    \
                                                      acc0, 0, 0, 0);         \
        acc1 = __builtin_amdgcn_mfma_f32_16x16x32_f16(a1, (BW)[(CO) + ks],    \
                                                      acc1, 0, 0, 0);         \
    } } while (0)

// chunk order: h0 (k512-767, BW[16..23]), h1 (k768-1023, BW[24..31]),
//              x0 (k0-255,   BW[0..7]),   x1 (k256-511,  BW[8..15])
// h-chunks prefetched BEFORE the flag poll (their producer flag was polled one
// phase earlier => data complete; addresses write-once => caches never stale).
#define PHASE(PH, WAIT, XSRC, HSRC, BW, BZ, CREG, HREG, HDST) do {            \
    const char* bx = (const char*)(XSRC) + (size_t)m0 * 1024;                 \
    const char* bh = (const char*)(HSRC) + (size_t)m0 * 1024;                 \
    i32x4 tmp[16];                                                            \
    ISSUE_CHUNK(bh, 0, 0);                                                    \
    ISSUE_CHUNK(bh, 1, 8);                                                    \
    if ((WAIT) && tid == 0) {                                                 \
        unsigned* fb = flags + (((PH) - 1) * 4 + m) * 256;                    \
        for (;;) {                                                            \
            unsigned s = 0;                                                   \
            _Pragma("unroll")                                                 \
            for (int o = 0; o < 8; ++o)                                       \
                s += __hip_atomic_load(fb + o * 32, __ATOMIC_RELAXED,         \
                                       __HIP_MEMORY_SCOPE_SYSTEM);            \
            if (s == 64u) break;                                              \
            __builtin_amdgcn_s_sleep(1);                                      \
        }                                                                     \
    }                                                                         \
    __syncthreads();                                                          \
    f32x4 acc0 = {0.f,0.f,0.f,0.f}, acc1 = {0.f,0.f,0.f,0.f};                 \
    WRITE_CHUNK(0, 0, 15);                                                    \
    __syncthreads();                                                          \
    ISSUE_CHUNK(bx, 0, 0);                                                    \
    MFMA_CHUNK(0, 16, BW);                                                    \
    WRITE_CHUNK(1, 8, 15);                                                    \
    __syncthreads();                                                          \
    ISSUE_CHUNK(bx, 1, 8);                                                    \
    MFMA_CHUNK(1, 24, BW);                                                    \
    WRITE_CHUNK(0, 0, 15);                                                    \
    __syncthreads();                                                          \
    MFMA_CHUNK(0, 0, BW);                                                     \
    WRITE_CHUNK(1, 8, 7);                                                     \
    __syncthreads();                                                          \
    MFMA_CHUNK(1, 8, BW);                                                     \
    /* ---- epilogue: transpose, cell, LDS-gather, coalesced 16B flush ---- */ \
    float* scrw = (float*)(ldsraw + w * 1024);                                \
    h16* hbuf = (h16*)(ldsraw + 8192);                                        \
    _Pragma("unroll")                                                         \
    for (int mt = 0; mt < 2; ++mt) {                                          \
        f32x4 accv = mt ? acc1 : acc0;                                        \
        _Pragma("unroll")                                                     \
        for (int rr = 0; rr < 4; ++rr)                                        \
            scrw[(kq * 4 + rr) * 16 + mcol] = accv[rr];                       \
        float4 g4 = *(const float4*)&scrw[(lane >> 2) * 16 + (lane & 3) * 4]; \
        float iv = sigf(g4.x + (BZ).x);                                       \
        float fv = sigf(g4.y + (BZ).y);                                       \
        float gv = tanhf_(g4.z + (BZ).z);                                     \
        float ov = sigf(g4.w + (BZ).w);                                       \
        float cc = fv * (CREG)[mt] + iv * gv;                                 \
        float hh = ov * tanhf_(cc);                                           \
        (CREG)[mt] = cc; (HREG)[mt] = hh;                                     \
        hbuf[(lrloc + mt * 16) * 8 + luloc] = (h16)hh;                        \
    }                                                                         \
    __syncthreads();                                                          \
    if (tid < 64) {                                                           \
        i32x4 hv16 = *(const i32x4*)(ldsraw + 8192 + tid * 16);               \
        int voff = (m0 + tid) * 1024 + u0 * 2;                                \
        asm volatile("global_store_dwordx4 %0, %1, %2 sc0 sc1"                \
            :: "v"(voff), "v"(hv16), "s"(HDST) : "memory");                   \
    }                                                                         \
    asm volatile("s_waitcnt vmcnt(0)" ::: "memory");                          \
    __syncthreads();                                                          \
    if (tid == 0)                                                             \
        __hip_atomic_fetch_add(flags + (((PH) * 4 + m) * 8 + myoct) * 32, 1u, \
                               __ATOMIC_RELAXED, __HIP_MEMORY_SCOPE_AGENT);   \
} while (0)

#pragma unroll 1
    for (int t = 0; t < TT; ++t) {
        const h16* x0src = t ? (H1 + (size_t)(t - 1) * 131072) : Xinit;
        const h16* h0src = t ? (H0 + (size_t)(t - 1) * 131072) : H0init;
        // layer 0 (phase 2t): A = [x0src | h0src] -> H0[t]
        PHASE(2 * t, t > 0, x0src, h0src, Bw0, bz0, creg[0], hreg[0],
              (H0 + (size_t)t * 131072));
        const h16* h1src = t ? (H1 + (size_t)(t - 1) * 131072) : H1init;
        // layer 1 (phase 2t+1): A = [H0[t] | h1src] -> H1[t]
        PHASE(2 * t + 1, 1, (H0 + (size_t)t * 131072), h1src, Bw1, bz1,
              creg[1], hreg[1], (H1 + (size_t)t * 131072));
    }

    // ---- final hT / cT (normal stores; kernel-end release flushes) ----
#pragma unroll
    for (int mt = 0; mt < 2; ++mt) {
        int idx = (erow0 + mt * 16) * 512 + eunit;
        h_st[idx]          = hreg[0][mt];
        h_st[131072 + idx] = hreg[1][mt];
        c_st[idx]          = creg[0][mt];
        c_st[131072 + idx] = creg[1][mt];
    }
}

// ---------------- final FC over all stored h1(t): (T*B) x 7, K=512 -----------
__global__ __launch_bounds__(256) void fc_kernel(
    const h16* __restrict__ H1, const float* __restrict__ Wfc,
    const float* __restrict__ bfc, float* __restrict__ out)
{
    __shared__ float wl[NO * 512];
    for (int i = threadIdx.x; i < NO * 512; i += 256) wl[i] = Wfc[i];
    __syncthreads();
    const int wave = threadIdx.x >> 6, lane = threadIdx.x & 63;
    const int row = blockIdx.x * 4 + wave;   // row = t*256 + b
    const h16* hr = H1 + (size_t)row * 512;
    float acc[NO] = {0, 0, 0, 0, 0, 0, 0};
#pragma unroll
    for (int i = 0; i < 8; ++i) {
        float hv = (float)hr[i * 64 + lane];
#pragma unroll
        for (int o = 0; o < NO; ++o) acc[o] += hv * wl[o * 512 + i * 64 + lane];
    }
#pragma unroll
    for (int o = 0; o < NO; ++o)
#pragma unroll
        for (int off = 32; off; off >>= 1) acc[o] += __shfl_down(acc[o], off);
    if (lane == 0) {
        const int t = row >> 8, b = row & 255;
#pragma unroll
        for (int o = 0; o < NO; ++o) out[b * (TT * NO) + t * NO + o] = acc[o] + bfc[o];
    }
}

extern "C" void kernel_launch(void* const* d_in, const int* in_sizes, int n_in,
                              void* d_out, int out_size, void* d_ws, size_t ws_size,
                              hipStream_t stream)
{
    (void)in_sizes; (void)n_in; (void)out_size; (void)ws_size;
    const float* x   = (const float*)d_in[0];
    const float* h0  = (const float*)d_in[1];
    const float* c0  = (const float*)d_in[2];
    const float* Wih = (const float*)d_in[3];
    const float* Whh = (const float*)d_in[4];
    const float* bih = (const float*)d_in[5];
    const float* bhh = (const float*)d_in[6];
    const float* Wfc = (const float*)d_in[7];
    const float* bfc = (const float*)d_in[8];

    float* outf = (float*)d_out;                 // decoded (256*64*7)
    float* h_st = outf + 114688;                 // hT (2,256,512)
    float* c_st = h_st + 262144;                 // cT (2,256,512)

    char* ws = (char*)d_ws;
    h16*      Wc     = (h16*)ws;                         // 8 MB
    float*    bias   = (float*)(ws + 8388608);           // 16 KB
    h16*      Xinit  = (h16*)(ws + 8404992);             // 256 KB
    h16*      H0init = (h16*)(ws + 8667136);             // 256 KB
    h16*      H1init = (h16*)(ws + 8929280);             // 256 KB
    h16*      H0     = (h16*)(ws + 9191424);             // 16 MB (64 steps)
    h16*      H1     = (h16*)(ws + 25968640);            // 16 MB (64 steps)
    unsigned* flags  = (unsigned*)(ws + 42745856);       // 512 KB

    prologue<<<3728, 256, 0, stream>>>(Wih, Whh, Wc, x, h0, bih, bhh,
                                       Xinit, H0init, H1init, bias, flags);
    lstm_persist<<<256, 256, 0, stream>>>(Wc, bias, c0, Xinit, H0init, H1init,
                                          H0, H1, h_st, c_st, flags);
    fc_kernel<<<4096, 256, 0, stream>>>(H1, Wfc, bfc, outf);
}